// Round 2
// baseline (95.538 us; speedup 1.0000x reference)
//
#include <hip/hip_runtime.h>

#define IN_H 200
#define IN_W 200
#define NCH  256
#define NROI 512
#define OUT_HW 49
#define PLANE (IN_H * IN_W)

__global__ __launch_bounds__(256) void roi_align_kernel(
    const float* __restrict__ input,
    const float* __restrict__ rois,
    float* __restrict__ out) {
  const int blk  = blockIdx.x;
  const int k    = blk >> 4;          // roi index (16 blocks per roi)
  const int cg   = blk & 15;          // 16-channel group
  const int wave = threadIdx.x >> 6;  // 0..3
  const int lane = threadIdx.x & 63;
  const int c0   = (cg << 4) + (wave << 2);  // base channel, 4 per thread

  const float* r = rois + k * 5;
  const int   b   = (int)r[0];
  const float x1s = r[1] * 0.25f;
  const float y1s = r[2] * 0.25f;
  const float x2s = r[3] * 0.25f;
  const float y2s = r[4] * 0.25f;
  const float roi_w = fmaxf(x2s - x1s, 1.0f);
  const float roi_h = fmaxf(y2s - y1s, 1.0f);
  const float bw = roi_w / 7.0f;
  const float bh = roi_h / 7.0f;

  // validity: coords monotonic in (p,i) -> check extreme sample coords only
  const float ymin = y1s + (bh * 0.5f) * 0.5f;
  const float xmin = x1s + (bw * 0.5f) * 0.5f;
  const float ymax = y1s + (bh * 6.0f + (bh * 0.5f) * 1.5f);
  const float xmax = x1s + (bw * 6.0f + (bw * 0.5f) * 1.5f);
  const bool valid = (ymin >= -1.0f) && (ymax <= (float)IN_H) &&
                     (xmin >= -1.0f) && (xmax <= (float)IN_W);
  const float scale = valid ? 0.25f : 0.0f;

  if (lane >= OUT_HW) return;

  const int ph = lane / 7;
  const int pw = lane - ph * 7;
  const float* plane0 = input + ((size_t)(b * NCH + c0)) * PLANE;

  const float ybase = y1s + bh * (float)ph;
  const float xbase = x1s + bw * (float)pw;

  float acc0 = 0.0f, acc1 = 0.0f, acc2 = 0.0f, acc3 = 0.0f;

#pragma unroll
  for (int iy = 0; iy < 2; ++iy) {
    const float y  = ybase + (bh * 0.5f) * ((float)iy + 0.5f);
    const float yc = fminf(fmaxf(y, 0.0f), (float)(IN_H - 1));
    const float ylf = floorf(yc);
    const int   yl  = (int)ylf;
    const int   yh  = min(yl + 1, IN_H - 1);
    const float ly  = yc - ylf;
    const float hy  = 1.0f - ly;
#pragma unroll
    for (int ix = 0; ix < 2; ++ix) {
      const float x  = xbase + (bw * 0.5f) * ((float)ix + 0.5f);
      const float xc = fminf(fmaxf(x, 0.0f), (float)(IN_W - 1));
      const float xlf = floorf(xc);
      const int   xl  = (int)xlf;
      const int   xh  = min(xl + 1, IN_W - 1);
      const float lx  = xc - xlf;
      const float hx  = 1.0f - lx;

      const float w1 = hy * hx, w2 = hy * lx, w3 = ly * hx, w4 = ly * lx;
      const int o1 = yl * IN_W + xl;
      const int o2 = yl * IN_W + xh;
      const int o3 = yh * IN_W + xl;
      const int o4 = yh * IN_W + xh;

      // 16 independent loads (4 channels x 4 corners) -> deep MLP
      const float* p0 = plane0;
      const float* p1 = plane0 + PLANE;
      const float* p2 = plane0 + 2 * PLANE;
      const float* p3 = plane0 + 3 * PLANE;

      const float a0 = p0[o1], b0 = p0[o2], c0v = p0[o3], d0 = p0[o4];
      const float a1 = p1[o1], b1 = p1[o2], c1v = p1[o3], d1 = p1[o4];
      const float a2 = p2[o1], b2 = p2[o2], c2v = p2[o3], d2 = p2[o4];
      const float a3 = p3[o1], b3 = p3[o2], c3v = p3[o3], d3 = p3[o4];

      acc0 += w1 * a0 + w2 * b0 + w3 * c0v + w4 * d0;
      acc1 += w1 * a1 + w2 * b1 + w3 * c1v + w4 * d1;
      acc2 += w1 * a2 + w2 * b2 + w3 * c2v + w4 * d2;
      acc3 += w1 * a3 + w2 * b3 + w3 * c3v + w4 * d3;
    }
  }

  const size_t obase = ((size_t)k * NCH + c0) * OUT_HW + lane;
  out[obase]              = acc0 * scale;
  out[obase + OUT_HW]     = acc1 * scale;
  out[obase + 2 * OUT_HW] = acc2 * scale;
  out[obase + 3 * OUT_HW] = acc3 * scale;
}

extern "C" void kernel_launch(void* const* d_in, const int* in_sizes, int n_in,
                              void* d_out, int out_size, void* d_ws, size_t ws_size,
                              hipStream_t stream) {
  const float* input = (const float*)d_in[0];
  const float* rois  = (const float*)d_in[1];
  float* out = (float*)d_out;

  const int blocks = NROI * (NCH / 16);  // 8192
  roi_align_kernel<<<blocks, 256, 0, stream>>>(input, rois, out);
}